// Round 7
// baseline (442.238 us; speedup 1.0000x reference)
//
#include <hip/hip_runtime.h>
#include <math.h>

// VQ-VAE eval forward via MFMA GEMM, split sweep/writer.
// inputs: [128,1024,64] fp32, embedding: [512,64] fp32
// out: loss[1] | quantized[8388608] | perplexity[1] | encodings[67108864]
//
// R7: split vq_main into (a) vq_sweep: MFMA hi/lo argmin + top-2 rescore,
// writes idx[131072] + hist + loss only; (b) vq_write: fill-style pure store
// kernel (plain dwordx4, no post-store barriers) for quantized + one-hot
// encodings. R6 showed stores ran at ~2 TB/s inside the monolithic kernel
// (NT stores + barrier-chopped stream); the fill kernel does 6 TB/s plain.

#define NK 512
#define ND 64
#define NROWS 131072
#define ROWS_PB 64
#define BLOCK 256
#define NBLOCKS (NROWS / ROWS_PB)   // 2048
#define NTILES 32                   // 32 code-tiles of 16
#define XSTRIDE 68                  // lds_x row stride (floats)
#define MARGIN 0.02f                // ~100x the hi/lo approx error bound

#define Q_OFF    1
#define PERP_OFF 8388609
#define ENC_OFF  8388610

typedef float vf2 __attribute__((ext_vector_type(2)));
typedef float vf4 __attribute__((ext_vector_type(4)));
typedef short vs8 __attribute__((ext_vector_type(8)));

__device__ __forceinline__ unsigned short bf16_rne(float v) {
    union { float f; unsigned int u; } a; a.f = v;
    return (unsigned short)((a.u + 0x7FFFu + ((a.u >> 16) & 1u)) >> 16);
}
__device__ __forceinline__ float bf16_to_f(unsigned short s) {
    union { unsigned int u; float f; } a; a.u = ((unsigned int)s) << 16;
    return a.f;
}

// ---- prep: E -> B-fragment stream (hi/lo bf16) + |e|^2 fp32 ----
// frag f per tile t: f0={eh,k0-31} f1={eh,k32-63} f2={el,k0-31} f3={el,k32-63}
// B-frag lane map (16x16x32): n = lane&15 (code-in-tile), k = (lane>>4)*8 + j
__global__ __launch_bounds__(64) void vq_prep(const float* __restrict__ emb,
                                              float* __restrict__ eknorm,
                                              unsigned int* __restrict__ efrag) {
    const int t = blockIdx.x;        // tile
    const int l = threadIdx.x;       // lane
    const int c = t * 16 + (l & 15);
    const int quad = l >> 4;
    #pragma unroll
    for (int f = 0; f < 4; ++f) {
        const int kbase = (f & 1) * 32 + quad * 8;
        unsigned int w[4];
        #pragma unroll
        for (int d = 0; d < 4; ++d) {
            float v0 = emb[c * ND + kbase + 2 * d];
            float v1 = emb[c * ND + kbase + 2 * d + 1];
            unsigned short h0 = bf16_rne(v0), h1 = bf16_rne(v1);
            unsigned short l0 = bf16_rne(v0 - bf16_to_f(h0));
            unsigned short l1 = bf16_rne(v1 - bf16_to_f(h1));
            unsigned short e0 = (f < 2) ? h0 : l0;
            unsigned short e1 = (f < 2) ? h1 : l1;
            w[d] = (unsigned int)e0 | ((unsigned int)e1 << 16);
        }
        unsigned int* dst = efrag + ((size_t)(t * 4 + f) * 64 + l) * 4;
        dst[0] = w[0]; dst[1] = w[1]; dst[2] = w[2]; dst[3] = w[3];
    }
    if (quad == 0) {
        const vf4* er = (const vf4*)(emb + c * ND);
        float s0 = 0.f, s1 = 0.f, s2 = 0.f, s3 = 0.f;
        #pragma unroll
        for (int j = 0; j < 16; ++j) {
            vf4 v = er[j];
            s0 += v.x * v.x; s1 += v.y * v.y; s2 += v.z * v.z; s3 += v.w * v.w;
        }
        eknorm[c] = (s0 + s1) + (s2 + s3);
    }
}

// ---- sweep: argmin via 6-MFMA hi/lo split + top-2 + exact rescore ----
__global__ __launch_bounds__(BLOCK) void vq_sweep(const float* __restrict__ x,
                                                  const float* __restrict__ emb,
                                                  const float* __restrict__ eknorm,
                                                  const unsigned int* __restrict__ efrag,
                                                  int* __restrict__ idx_g,
                                                  int* __restrict__ g_counts,
                                                  float* __restrict__ g_loss) {
    __shared__ float lds_x[ROWS_PB * XSTRIDE];
    __shared__ float ek_lds[NK];
    __shared__ float d1s[ROWS_PB], d2s[ROWS_PB];
    __shared__ int   i1s[ROWS_PB], i2s[ROWS_PB];

    const int tid  = threadIdx.x;
    const int wave = tid >> 6;
    const int lane = tid & 63;
    const int col  = lane & 15;
    const int quad = lane >> 4;

    // stage X tile + eknorm into LDS
    {
        const vf4* xp = (const vf4*)(x + (size_t)blockIdx.x * ROWS_PB * ND);
        #pragma unroll
        for (int i = 0; i < 4; ++i) {
            int e4 = tid + i * BLOCK;
            int r  = e4 >> 4;
            int c4 = (e4 & 15) * 4;
            *(vf4*)&lds_x[r * XSTRIDE + c4] = xp[e4];
        }
        ek_lds[tid] = eknorm[tid];
        ek_lds[tid + 256] = eknorm[tid + 256];
    }
    __syncthreads();

    // A-fragments (hi/lo): m = lane&15, k = quad*8 + j
    const int arow = wave * 16 + col;
    vs8 ah0, ah1, al0, al1;
    {
        const float* xr = &lds_x[arow * XSTRIDE];
        #pragma unroll
        for (int j = 0; j < 8; ++j) {
            float va = xr[quad * 8 + j];
            float vb = xr[32 + quad * 8 + j];
            unsigned short ha = bf16_rne(va);
            unsigned short hb = bf16_rne(vb);
            ah0[j] = (short)ha; al0[j] = (short)bf16_rne(va - bf16_to_f(ha));
            ah1[j] = (short)hb; al1[j] = (short)bf16_rne(vb - bf16_to_f(hb));
        }
    }

    float d1[4], d2[4];
    int   i1[4], i2[4];
    #pragma unroll
    for (int r = 0; r < 4; ++r) { d1[r] = INFINITY; d2[r] = INFINITY; i1[r] = 0x7FFFFFFF; i2[r] = 0x7FFFFFFF; }

    const vs8* bbase = (const vs8*)efrag;
    vs8 b0 = bbase[0 * 64 + lane];
    vs8 b1 = bbase[1 * 64 + lane];
    vs8 b2 = bbase[2 * 64 + lane];
    vs8 b3 = bbase[3 * 64 + lane];

    for (int t = 0; t < NTILES; ++t) {
        vs8 n0, n1, n2, n3;
        if (t + 1 < NTILES) {
            n0 = bbase[((t + 1) * 4 + 0) * 64 + lane];
            n1 = bbase[((t + 1) * 4 + 1) * 64 + lane];
            n2 = bbase[((t + 1) * 4 + 2) * 64 + lane];
            n3 = bbase[((t + 1) * 4 + 3) * 64 + lane];
        }
        vf4 acc0 = {0.f, 0.f, 0.f, 0.f};
        vf4 acc1 = {0.f, 0.f, 0.f, 0.f};
        acc0 = __builtin_amdgcn_mfma_f32_16x16x32_bf16(ah0, b0, acc0, 0, 0, 0);
        acc1 = __builtin_amdgcn_mfma_f32_16x16x32_bf16(ah1, b1, acc1, 0, 0, 0);
        acc0 = __builtin_amdgcn_mfma_f32_16x16x32_bf16(al0, b0, acc0, 0, 0, 0);
        acc1 = __builtin_amdgcn_mfma_f32_16x16x32_bf16(al1, b1, acc1, 0, 0, 0);
        acc0 = __builtin_amdgcn_mfma_f32_16x16x32_bf16(ah0, b2, acc0, 0, 0, 0);
        acc1 = __builtin_amdgcn_mfma_f32_16x16x32_bf16(ah1, b3, acc1, 0, 0, 0);

        const float ek = ek_lds[t * 16 + col];
        const int cidx = t * 16 + col;
        #pragma unroll
        for (int r = 0; r < 4; ++r) {
            float d = ek - 2.f * (acc0[r] + acc1[r]);
            bool lt1 = d < d1[r];
            bool lt2 = d < d2[r];
            float nd2 = lt1 ? d1[r] : (lt2 ? d : d2[r]);
            int   ni2 = lt1 ? i1[r] : (lt2 ? cidx : i2[r]);
            d2[r] = nd2; i2[r] = ni2;
            d1[r] = lt1 ? d : d1[r];
            i1[r] = lt1 ? cidx : i1[r];
        }
        b0 = n0; b1 = n1; b2 = n2; b3 = n3;
    }

    // butterfly-merge top-2 across the 16 lanes holding each row
    #pragma unroll
    for (int m = 8; m >= 1; m >>= 1) {
        #pragma unroll
        for (int r = 0; r < 4; ++r) {
            float od1 = __shfl_xor(d1[r], m);
            int   oi1 = __shfl_xor(i1[r], m);
            float od2 = __shfl_xor(d2[r], m);
            int   oi2 = __shfl_xor(i2[r], m);
            bool aF = (d1[r] < od1) || (d1[r] == od1 && i1[r] < oi1);
            float n1 = aF ? d1[r] : od1;  int ni1 = aF ? i1[r] : oi1;
            float ca = aF ? od1 : d1[r];  int cia = aF ? oi1 : i1[r];
            float cb = aF ? d2[r] : od2;  int cib = aF ? i2[r] : oi2;
            bool bF = (cb < ca) || (cb == ca && cib < cia);
            float n2 = bF ? cb : ca;      int ni2 = bF ? cib : cia;
            d1[r] = n1; i1[r] = ni1; d2[r] = n2; i2[r] = ni2;
        }
    }
    if (col == 0) {
        #pragma unroll
        for (int r = 0; r < 4; ++r) {
            int lr = wave * 16 + quad * 4 + r;   // C layout: row = quad*4 + reg
            d1s[lr] = d1[r]; i1s[lr] = i1[r];
            d2s[lr] = d2[r]; i2s[lr] = i2[r];
        }
    }
    __syncthreads();

    // wave 0: rescore near-ties exact, commit idx + hist + loss
    if (tid < ROWS_PB) {
        int am = i1s[tid];
        float dfin = d1s[tid];
        if (d2s[tid] - dfin < MARGIN) {
            int ia = i1s[tid], ib = i2s[tid];
            const float* xr = &lds_x[tid * XSTRIDE];
            float da, db;
            {
                const vf4* er = (const vf4*)(emb + ia * ND);
                float s0 = 0.f, s1 = 0.f, s2 = 0.f, s3 = 0.f;
                #pragma unroll
                for (int j = 0; j < 16; ++j) {
                    vf4 v = er[j];
                    s0 += xr[4 * j] * v.x; s1 += xr[4 * j + 1] * v.y;
                    s2 += xr[4 * j + 2] * v.z; s3 += xr[4 * j + 3] * v.w;
                }
                da = ek_lds[ia] - 2.f * ((s0 + s1) + (s2 + s3));
            }
            {
                const vf4* er = (const vf4*)(emb + ib * ND);
                float s0 = 0.f, s1 = 0.f, s2 = 0.f, s3 = 0.f;
                #pragma unroll
                for (int j = 0; j < 16; ++j) {
                    vf4 v = er[j];
                    s0 += xr[4 * j] * v.x; s1 += xr[4 * j + 1] * v.y;
                    s2 += xr[4 * j + 2] * v.z; s3 += xr[4 * j + 3] * v.w;
                }
                db = ek_lds[ib] - 2.f * ((s0 + s1) + (s2 + s3));
            }
            bool useB = (db < da) || (db == da && ib < ia);   // numpy tie-break
            am   = useB ? ib : ia;
            dfin = useB ? db : da;
        }
        idx_g[blockIdx.x * ROWS_PB + tid] = am;
        atomicAdd(&g_counts[am], 1);

        // loss partial: |x-e|^2 = xnorm + dfin (error ~1e-4/row, washes out)
        float xn = 0.f;
        {
            const float* xr = &lds_x[tid * XSTRIDE];
            float s0 = 0.f, s1 = 0.f, s2 = 0.f, s3 = 0.f;
            #pragma unroll
            for (int j = 0; j < 16; ++j) {
                s0 += xr[4 * j] * xr[4 * j];         s1 += xr[4 * j + 1] * xr[4 * j + 1];
                s2 += xr[4 * j + 2] * xr[4 * j + 2]; s3 += xr[4 * j + 3] * xr[4 * j + 3];
            }
            xn = (s0 + s1) + (s2 + s3);
        }
        float lossv = xn + dfin;
        #pragma unroll
        for (int off = 32; off >= 1; off >>= 1) lossv += __shfl_down(lossv, off);
        if (tid == 0) atomicAdd(g_loss, lossv);
    }
}

// ---- writer: pure store kernel (plain stores, fill-kernel style) ----
// Block b: rows [64b, 64b+64). quantized: dword stores. encodings: one-hot
// computed arithmetically; slice base ≡ 8 mod 16 -> vf2 head/tail + 8191 vf4.
__global__ __launch_bounds__(BLOCK) void vq_write(const float* __restrict__ emb,
                                                  const int* __restrict__ idx_g,
                                                  float* __restrict__ out) {
    __shared__ int idx_s[ROWS_PB];
    const int tid = threadIdx.x;
    if (tid < ROWS_PB) idx_s[tid] = idx_g[blockIdx.x * ROWS_PB + tid];
    __syncthreads();

    // quantized gather: wave-uniform emb row per instr, coalesced dword stores
    {
        float* qout = out + Q_OFF + (size_t)blockIdx.x * (ROWS_PB * ND);
        #pragma unroll
        for (int i = 0; i < 16; ++i) {
            int p = tid + i * BLOCK;
            qout[p] = emb[idx_s[p >> 6] * ND + (p & 63)];
        }
    }

    // encodings one-hot
    float* ebase = out + ENC_OFF + (size_t)blockIdx.x * (ROWS_PB * NK);
    if (tid == 0) {
        int a0 = idx_s[0];
        vf2 h; h.x = (a0 == 0) ? 1.f : 0.f; h.y = (a0 == 1) ? 1.f : 0.f;
        *(vf2*)ebase = h;
        int a63 = idx_s[63];
        vf2 tl; tl.x = (a63 == 510) ? 1.f : 0.f; tl.y = (a63 == 511) ? 1.f : 0.f;
        *(vf2*)(ebase + ROWS_PB * NK - 2) = tl;
    }
    const int c0 = (2 + 4 * tid) & 511;    // constant per thread
    const int rb = (2 + 4 * tid) >> 9;     // 0 or 1
    if (c0 != 510) {
        // vf4 never crosses a row boundary for this thread
        #pragma unroll
        for (int i = 0; i < 32; ++i) {
            int p = tid + i * BLOCK;
            if (p < 8191) {
                int am = idx_s[rb + 2 * i];
                vf4 v;
                v.x = (am == c0)     ? 1.f : 0.f;
                v.y = (am == c0 + 1) ? 1.f : 0.f;
                v.z = (am == c0 + 2) ? 1.f : 0.f;
                v.w = (am == c0 + 3) ? 1.f : 0.f;
                *(vf4*)(ebase + 2 + 4 * (size_t)p) = v;
            }
        }
    } else {
        // tid 127 & 255: vf4 spans cols {510,511} of row r and {0,1} of row r+1
        #pragma unroll
        for (int i = 0; i < 32; ++i) {
            int p = tid + i * BLOCK;
            if (p < 8191) {
                int r0 = rb + 2 * i;
                int am0 = idx_s[r0];
                int am1 = idx_s[r0 + 1];
                vf4 v;
                v.x = (am0 == 510) ? 1.f : 0.f;
                v.y = (am0 == 511) ? 1.f : 0.f;
                v.z = (am1 == 0)   ? 1.f : 0.f;
                v.w = (am1 == 1)   ? 1.f : 0.f;
                *(vf4*)(ebase + 2 + 4 * (size_t)p) = v;
            }
        }
    }
}

__global__ __launch_bounds__(512) void vq_final(const int* __restrict__ g_counts,
                                                const float* __restrict__ g_loss,
                                                float* __restrict__ out) {
    __shared__ float red[8];
    int t = threadIdx.x;
    float p = (float)g_counts[t] * (1.0f / (float)NROWS);
    float h = p * logf(p + 1e-10f);
    #pragma unroll
    for (int off = 32; off >= 1; off >>= 1) h += __shfl_down(h, off);
    if ((t & 63) == 0) red[t >> 6] = h;
    __syncthreads();
    if (t == 0) {
        float s = 0.f;
        #pragma unroll
        for (int i = 0; i < 8; ++i) s += red[i];
        out[PERP_OFF] = expf(-s);
        out[0] = 0.25f * g_loss[0] / (float)(NROWS * ND);
    }
}

extern "C" void kernel_launch(void* const* d_in, const int* in_sizes, int n_in,
                              void* d_out, int out_size, void* d_ws, size_t ws_size,
                              hipStream_t stream) {
    const float* x   = (const float*)d_in[0];
    const float* emb = (const float*)d_in[1];
    float* out = (float*)d_out;

    int*          g_counts = (int*)d_ws;                           // 512 ints
    float*        g_loss   = (float*)((char*)d_ws + 2048);         // 1 float
    float*        eknorm   = (float*)((char*)d_ws + 4096);         // 512 floats
    unsigned int* efrag    = (unsigned int*)((char*)d_ws + 8192);  // 128 KB
    int*          idx_g    = (int*)((char*)d_ws + 8192 + 131072);  // 512 KB

    // ws re-poisoned to 0xAA before every launch — zero counts+loss
    // (eknorm/efrag/idx_g are fully overwritten each call).
    (void)hipMemsetAsync(d_ws, 0, 4096, stream);

    vq_prep<<<NTILES, 64, 0, stream>>>(emb, eknorm, efrag);
    vq_sweep<<<NBLOCKS, BLOCK, 0, stream>>>(x, emb, eknorm, efrag, idx_g, g_counts, g_loss);
    vq_write<<<NBLOCKS, BLOCK, 0, stream>>>(emb, idx_g, out);
    vq_final<<<1, 512, 0, stream>>>(g_counts, g_loss, out);
}

// Round 8
// 387.463 us; speedup vs baseline: 1.1414x; 1.1414x over previous
//
#include <hip/hip_runtime.h>
#include <math.h>

// VQ-VAE eval forward via MFMA GEMM, monolithic.
// inputs: [128,1024,64] fp32, embedding: [512,64] fp32
// out: loss[1] | quantized[8388608] | perplexity[1] | encodings[67108864]
//
// R8: revert to monolithic (R7 split lost cross-block store/compute overlap).
// vs R6: no zero-fill+scatter (direct arithmetic one-hot vf4 = one 268MB pass,
// not two), loss from xnorm+dmin (no gather-loop FMAs), plain stores (match
// the 6TB/s fill kernel; NT unproven), enc stores issued before quantized.

#define NK 512
#define ND 64
#define NROWS 131072
#define ROWS_PB 64
#define BLOCK 256
#define NBLOCKS (NROWS / ROWS_PB)   // 2048
#define NTILES 32                   // 32 code-tiles of 16
#define XSTRIDE 68                  // lds_x row stride (floats)
#define MARGIN 0.02f                // ~100x the hi/lo approx error bound

#define Q_OFF    1
#define PERP_OFF 8388609
#define ENC_OFF  8388610

typedef float vf2 __attribute__((ext_vector_type(2)));
typedef float vf4 __attribute__((ext_vector_type(4)));
typedef short vs8 __attribute__((ext_vector_type(8)));

__device__ __forceinline__ unsigned short bf16_rne(float v) {
    union { float f; unsigned int u; } a; a.f = v;
    return (unsigned short)((a.u + 0x7FFFu + ((a.u >> 16) & 1u)) >> 16);
}
__device__ __forceinline__ float bf16_to_f(unsigned short s) {
    union { unsigned int u; float f; } a; a.u = ((unsigned int)s) << 16;
    return a.f;
}

// ---- prep: E -> B-fragment stream (hi/lo bf16) + |e|^2 fp32 ----
// frag f per tile t: f0={eh,k0-31} f1={eh,k32-63} f2={el,k0-31} f3={el,k32-63}
// B-frag lane map (16x16x32): n = lane&15 (code-in-tile), k = (lane>>4)*8 + j
__global__ __launch_bounds__(64) void vq_prep(const float* __restrict__ emb,
                                              float* __restrict__ eknorm,
                                              unsigned int* __restrict__ efrag) {
    const int t = blockIdx.x;        // tile
    const int l = threadIdx.x;       // lane
    const int c = t * 16 + (l & 15);
    const int quad = l >> 4;
    #pragma unroll
    for (int f = 0; f < 4; ++f) {
        const int kbase = (f & 1) * 32 + quad * 8;
        unsigned int w[4];
        #pragma unroll
        for (int d = 0; d < 4; ++d) {
            float v0 = emb[c * ND + kbase + 2 * d];
            float v1 = emb[c * ND + kbase + 2 * d + 1];
            unsigned short h0 = bf16_rne(v0), h1 = bf16_rne(v1);
            unsigned short l0 = bf16_rne(v0 - bf16_to_f(h0));
            unsigned short l1 = bf16_rne(v1 - bf16_to_f(h1));
            unsigned short e0 = (f < 2) ? h0 : l0;
            unsigned short e1 = (f < 2) ? h1 : l1;
            w[d] = (unsigned int)e0 | ((unsigned int)e1 << 16);
        }
        unsigned int* dst = efrag + ((size_t)(t * 4 + f) * 64 + l) * 4;
        dst[0] = w[0]; dst[1] = w[1]; dst[2] = w[2]; dst[3] = w[3];
    }
    if (quad == 0) {
        const vf4* er = (const vf4*)(emb + c * ND);
        float s0 = 0.f, s1 = 0.f, s2 = 0.f, s3 = 0.f;
        #pragma unroll
        for (int j = 0; j < 16; ++j) {
            vf4 v = er[j];
            s0 += v.x * v.x; s1 += v.y * v.y; s2 += v.z * v.z; s3 += v.w * v.w;
        }
        eknorm[c] = (s0 + s1) + (s2 + s3);
    }
}

__global__ __launch_bounds__(BLOCK) void vq_main(const float* __restrict__ x,
                                                 const float* __restrict__ emb,
                                                 const float* __restrict__ eknorm,
                                                 const unsigned int* __restrict__ efrag,
                                                 float* __restrict__ out,
                                                 int* __restrict__ g_counts,
                                                 float* __restrict__ g_loss) {
    __shared__ float lds_x[ROWS_PB * XSTRIDE];
    __shared__ float ek_lds[NK];
    __shared__ float d1s[ROWS_PB], d2s[ROWS_PB];
    __shared__ int   i1s[ROWS_PB], i2s[ROWS_PB];
    __shared__ int   idx_s[ROWS_PB];

    const int tid  = threadIdx.x;
    const int wave = tid >> 6;
    const int lane = tid & 63;
    const int col  = lane & 15;
    const int quad = lane >> 4;

    // ---- stage X tile + eknorm into LDS ----
    {
        const vf4* xp = (const vf4*)(x + (size_t)blockIdx.x * ROWS_PB * ND);
        #pragma unroll
        for (int i = 0; i < 4; ++i) {
            int e4 = tid + i * BLOCK;
            int r  = e4 >> 4;
            int c4 = (e4 & 15) * 4;
            *(vf4*)&lds_x[r * XSTRIDE + c4] = xp[e4];
        }
        ek_lds[tid] = eknorm[tid];
        ek_lds[tid + 256] = eknorm[tid + 256];
    }
    __syncthreads();

    // ---- A-fragments (hi/lo): m = lane&15, k = quad*8 + j ----
    const int arow = wave * 16 + col;
    vs8 ah0, ah1, al0, al1;
    {
        const float* xr = &lds_x[arow * XSTRIDE];
        #pragma unroll
        for (int j = 0; j < 8; ++j) {
            float va = xr[quad * 8 + j];
            float vb = xr[32 + quad * 8 + j];
            unsigned short ha = bf16_rne(va);
            unsigned short hb = bf16_rne(vb);
            ah0[j] = (short)ha; al0[j] = (short)bf16_rne(va - bf16_to_f(ha));
            ah1[j] = (short)hb; al1[j] = (short)bf16_rne(vb - bf16_to_f(hb));
        }
    }

    // ---- sweep 32 code-tiles: 6 MFMA each, top-2 tracking ----
    float d1[4], d2[4];
    int   i1[4], i2[4];
    #pragma unroll
    for (int r = 0; r < 4; ++r) { d1[r] = INFINITY; d2[r] = INFINITY; i1[r] = 0x7FFFFFFF; i2[r] = 0x7FFFFFFF; }

    const vs8* bbase = (const vs8*)efrag;
    vs8 b0 = bbase[0 * 64 + lane];
    vs8 b1 = bbase[1 * 64 + lane];
    vs8 b2 = bbase[2 * 64 + lane];
    vs8 b3 = bbase[3 * 64 + lane];

    for (int t = 0; t < NTILES; ++t) {
        vs8 n0, n1, n2, n3;
        if (t + 1 < NTILES) {
            n0 = bbase[((t + 1) * 4 + 0) * 64 + lane];
            n1 = bbase[((t + 1) * 4 + 1) * 64 + lane];
            n2 = bbase[((t + 1) * 4 + 2) * 64 + lane];
            n3 = bbase[((t + 1) * 4 + 3) * 64 + lane];
        }
        vf4 acc0 = {0.f, 0.f, 0.f, 0.f};
        vf4 acc1 = {0.f, 0.f, 0.f, 0.f};
        acc0 = __builtin_amdgcn_mfma_f32_16x16x32_bf16(ah0, b0, acc0, 0, 0, 0);
        acc1 = __builtin_amdgcn_mfma_f32_16x16x32_bf16(ah1, b1, acc1, 0, 0, 0);
        acc0 = __builtin_amdgcn_mfma_f32_16x16x32_bf16(al0, b0, acc0, 0, 0, 0);
        acc1 = __builtin_amdgcn_mfma_f32_16x16x32_bf16(al1, b1, acc1, 0, 0, 0);
        acc0 = __builtin_amdgcn_mfma_f32_16x16x32_bf16(ah0, b2, acc0, 0, 0, 0);
        acc1 = __builtin_amdgcn_mfma_f32_16x16x32_bf16(ah1, b3, acc1, 0, 0, 0);

        const float ek = ek_lds[t * 16 + col];
        const int cidx = t * 16 + col;
        #pragma unroll
        for (int r = 0; r < 4; ++r) {
            float d = ek - 2.f * (acc0[r] + acc1[r]);
            bool lt1 = d < d1[r];
            bool lt2 = d < d2[r];
            float nd2 = lt1 ? d1[r] : (lt2 ? d : d2[r]);
            int   ni2 = lt1 ? i1[r] : (lt2 ? cidx : i2[r]);
            d2[r] = nd2; i2[r] = ni2;
            d1[r] = lt1 ? d : d1[r];
            i1[r] = lt1 ? cidx : i1[r];
        }
        b0 = n0; b1 = n1; b2 = n2; b3 = n3;
    }

    // ---- butterfly-merge top-2 across the 16 lanes holding each row ----
    #pragma unroll
    for (int m = 8; m >= 1; m >>= 1) {
        #pragma unroll
        for (int r = 0; r < 4; ++r) {
            float od1 = __shfl_xor(d1[r], m);
            int   oi1 = __shfl_xor(i1[r], m);
            float od2 = __shfl_xor(d2[r], m);
            int   oi2 = __shfl_xor(i2[r], m);
            bool aF = (d1[r] < od1) || (d1[r] == od1 && i1[r] < oi1);
            float n1 = aF ? d1[r] : od1;  int ni1 = aF ? i1[r] : oi1;
            float ca = aF ? od1 : d1[r];  int cia = aF ? oi1 : i1[r];
            float cb = aF ? d2[r] : od2;  int cib = aF ? i2[r] : oi2;
            bool bF = (cb < ca) || (cb == ca && cib < cia);
            float n2 = bF ? cb : ca;      int ni2 = bF ? cib : cia;
            d1[r] = n1; i1[r] = ni1; d2[r] = n2; i2[r] = ni2;
        }
    }
    if (col == 0) {
        #pragma unroll
        for (int r = 0; r < 4; ++r) {
            int lr = wave * 16 + quad * 4 + r;   // C layout: row = quad*4 + reg
            d1s[lr] = d1[r]; i1s[lr] = i1[r];
            d2s[lr] = d2[r]; i2s[lr] = i2[r];
        }
    }
    __syncthreads();

    // ---- wave 0: rescore near-ties exact; commit idx + hist + loss ----
    if (tid < ROWS_PB) {
        int am = i1s[tid];
        float dfin = d1s[tid];
        if (d2s[tid] - dfin < MARGIN) {
            int ia = i1s[tid], ib = i2s[tid];
            const float* xr = &lds_x[tid * XSTRIDE];
            float da, db;
            {
                const vf4* er = (const vf4*)(emb + ia * ND);
                float s0 = 0.f, s1 = 0.f, s2 = 0.f, s3 = 0.f;
                #pragma unroll
                for (int j = 0; j < 16; ++j) {
                    vf4 v = er[j];
                    s0 += xr[4 * j] * v.x; s1 += xr[4 * j + 1] * v.y;
                    s2 += xr[4 * j + 2] * v.z; s3 += xr[4 * j + 3] * v.w;
                }
                da = ek_lds[ia] - 2.f * ((s0 + s1) + (s2 + s3));
            }
            {
                const vf4* er = (const vf4*)(emb + ib * ND);
                float s0 = 0.f, s1 = 0.f, s2 = 0.f, s3 = 0.f;
                #pragma unroll
                for (int j = 0; j < 16; ++j) {
                    vf4 v = er[j];
                    s0 += xr[4 * j] * v.x; s1 += xr[4 * j + 1] * v.y;
                    s2 += xr[4 * j + 2] * v.z; s3 += xr[4 * j + 3] * v.w;
                }
                db = ek_lds[ib] - 2.f * ((s0 + s1) + (s2 + s3));
            }
            bool useB = (db < da) || (db == da && ib < ia);   // numpy tie-break
            am   = useB ? ib : ia;
            dfin = useB ? db : da;
        }
        idx_s[tid] = am;
        atomicAdd(&g_counts[am], 1);

        // loss partial: |x-e|^2 = xnorm + dfin (error ~1e-4/row, washes out)
        float xn;
        {
            const float* xr = &lds_x[tid * XSTRIDE];
            float s0 = 0.f, s1 = 0.f, s2 = 0.f, s3 = 0.f;
            #pragma unroll
            for (int j = 0; j < 16; ++j) {
                s0 += xr[4 * j] * xr[4 * j];         s1 += xr[4 * j + 1] * xr[4 * j + 1];
                s2 += xr[4 * j + 2] * xr[4 * j + 2]; s3 += xr[4 * j + 3] * xr[4 * j + 3];
            }
            xn = (s0 + s1) + (s2 + s3);
        }
        float lossv = xn + dfin;
        #pragma unroll
        for (int off = 32; off >= 1; off >>= 1) lossv += __shfl_down(lossv, off);
        if (tid == 0) atomicAdd(g_loss, lossv);
    }
    __syncthreads();   // idx_s visible to all

    // ---- encodings: arithmetic one-hot, plain vf4 stores (load-independent,
    //      issued first so the 268MB stream drains under the gather below).
    //      Slice base byte addr ≡ 8 mod 16 -> vf2 head/tail + 8191 vf4. ----
    float* ebase = out + ENC_OFF + (size_t)blockIdx.x * (ROWS_PB * NK);
    if (tid == 0) {
        int a0 = idx_s[0];
        vf2 h; h.x = (a0 == 0) ? 1.f : 0.f; h.y = (a0 == 1) ? 1.f : 0.f;
        *(vf2*)ebase = h;
        int a63 = idx_s[63];
        vf2 tl; tl.x = (a63 == 510) ? 1.f : 0.f; tl.y = (a63 == 511) ? 1.f : 0.f;
        *(vf2*)(ebase + ROWS_PB * NK - 2) = tl;
    }
    {
        const int c0 = (2 + 4 * tid) & 511;    // column base, constant per thread
        const int rb = (2 + 4 * tid) >> 9;     // 0 or 1
        if (c0 != 510) {
            #pragma unroll
            for (int i = 0; i < 32; ++i) {
                int p = tid + i * BLOCK;
                if (p < 8191) {
                    int am = idx_s[rb + 2 * i];
                    vf4 v;
                    v.x = (am == c0)     ? 1.f : 0.f;
                    v.y = (am == c0 + 1) ? 1.f : 0.f;
                    v.z = (am == c0 + 2) ? 1.f : 0.f;
                    v.w = (am == c0 + 3) ? 1.f : 0.f;
                    *(vf4*)(ebase + 2 + 4 * (size_t)p) = v;
                }
            }
        } else {
            // tid 127 & 255: vf4 spans cols {510,511} of row r and {0,1} of r+1
            #pragma unroll
            for (int i = 0; i < 32; ++i) {
                int p = tid + i * BLOCK;
                if (p < 8191) {
                    int r0 = rb + 2 * i;
                    int am0 = idx_s[r0];
                    int am1 = idx_s[r0 + 1];
                    vf4 v;
                    v.x = (am0 == 510) ? 1.f : 0.f;
                    v.y = (am0 == 511) ? 1.f : 0.f;
                    v.z = (am1 == 0)   ? 1.f : 0.f;
                    v.w = (am1 == 1)   ? 1.f : 0.f;
                    *(vf4*)(ebase + 2 + 4 * (size_t)p) = v;
                }
            }
        }
    }

    // ---- quantized: wave-uniform emb row gather (L2-hot), coalesced stores ----
    {
        float* qout = out + Q_OFF + (size_t)blockIdx.x * (ROWS_PB * ND);
        #pragma unroll
        for (int i = 0; i < 16; ++i) {
            int p = tid + i * BLOCK;
            qout[p] = emb[idx_s[p >> 6] * ND + (p & 63)];
        }
    }
}

__global__ __launch_bounds__(512) void vq_final(const int* __restrict__ g_counts,
                                                const float* __restrict__ g_loss,
                                                float* __restrict__ out) {
    __shared__ float red[8];
    int t = threadIdx.x;
    float p = (float)g_counts[t] * (1.0f / (float)NROWS);
    float h = p * logf(p + 1e-10f);
    #pragma unroll
    for (int off = 32; off >= 1; off >>= 1) h += __shfl_down(h, off);
    if ((t & 63) == 0) red[t >> 6] = h;
    __syncthreads();
    if (t == 0) {
        float s = 0.f;
        #pragma unroll
        for (int i = 0; i < 8; ++i) s += red[i];
        out[PERP_OFF] = expf(-s);
        out[0] = 0.25f * g_loss[0] / (float)(NROWS * ND);
    }
}

extern "C" void kernel_launch(void* const* d_in, const int* in_sizes, int n_in,
                              void* d_out, int out_size, void* d_ws, size_t ws_size,
                              hipStream_t stream) {
    const float* x   = (const float*)d_in[0];
    const float* emb = (const float*)d_in[1];
    float* out = (float*)d_out;

    int*          g_counts = (int*)d_ws;                           // 512 ints
    float*        g_loss   = (float*)((char*)d_ws + 2048);         // 1 float
    float*        eknorm   = (float*)((char*)d_ws + 4096);         // 512 floats
    unsigned int* efrag    = (unsigned int*)((char*)d_ws + 8192);  // 128 KB

    // ws re-poisoned to 0xAA before every launch — zero counts+loss
    // (eknorm/efrag are fully overwritten each call).
    (void)hipMemsetAsync(d_ws, 0, 4096, stream);

    vq_prep<<<NTILES, 64, 0, stream>>>(emb, eknorm, efrag);
    vq_main<<<NBLOCKS, BLOCK, 0, stream>>>(x, emb, eknorm, efrag, out, g_counts, g_loss);
    vq_final<<<1, 512, 0, stream>>>(g_counts, g_loss, out);
}